// Round 3
// baseline (685.588 us; speedup 1.0000x reference)
//
#include <hip/hip_runtime.h>

#define IN_F 128
#define OUT_F 32
#define BUCKET_BITS 8
#define BUCKET_SZ 256           // dst nodes per bucket
#define CHUNK 8192              // edges per phase-A block
#define ABLK 512                // threads per phase-A block
#define EPB (CHUNK / ABLK)      // 16 edges per thread

// ---- degree / dis -------------------------------------------------------

__global__ void k_hist(const int* __restrict__ dst, int* __restrict__ cnt, int E) {
    int e = blockIdx.x * blockDim.x + threadIdx.x;
    if (e < E) atomicAdd(&cnt[dst[e]], 1);
}

__global__ void k_dis(const int* __restrict__ cnt, float* __restrict__ dis, int n) {
    int i = blockIdx.x * blockDim.x + threadIdx.x;
    if (i < n) dis[i] = rsqrtf((float)(cnt[i] + 1));   // +1 self loop
}

// ---- g = (x @ W^T) * dis ------------------------------------------------
// block = 256 threads = 8 nodes x 32 features
__global__ void k_gemm(const float* __restrict__ x, const float* __restrict__ W,
                       const float* __restrict__ dis, float* __restrict__ g, int n) {
    __shared__ float  Wl[IN_F * OUT_F];   // transposed: Wl[k*32 + f]
    __shared__ float4 xl4[8 * 32];

    int tid = threadIdx.x;
    for (int i = tid; i < IN_F * OUT_F; i += 256) {
        int f = i >> 7;
        int k = i & 127;
        Wl[k * 32 + f] = W[i];
    }
    int nodeBase = blockIdx.x * 8;
    int row = tid >> 5, c4 = tid & 31;
    int nrow = nodeBase + row;
    if (nrow < n) xl4[row * 32 + c4] = ((const float4*)x)[nrow * 32 + c4];
    __syncthreads();

    int f = tid & 31, nl = tid >> 5;
    int node = nodeBase + nl;
    if (node < n) {
        float acc = 0.f;
        #pragma unroll
        for (int k4 = 0; k4 < 32; ++k4) {
            float4 xv = xl4[nl * 32 + k4];
            int kb = k4 * 4;
            acc = fmaf(xv.x, Wl[(kb + 0) * 32 + f], acc);
            acc = fmaf(xv.y, Wl[(kb + 1) * 32 + f], acc);
            acc = fmaf(xv.z, Wl[(kb + 2) * 32 + f], acc);
            acc = fmaf(xv.w, Wl[(kb + 3) * 32 + f], acc);
        }
        g[node * OUT_F + f] = acc * dis[node];
    }
}

// ---- Phase A1: per-(block,bucket) histogram -----------------------------
__global__ void __launch_bounds__(ABLK) k_bhist(const int* __restrict__ dst,
                                                int* __restrict__ blkHist, int E, int NB) {
    __shared__ int hist[512];
    int t = threadIdx.x;
    hist[t] = 0;
    __syncthreads();
    int base = blockIdx.x * CHUNK;
    #pragma unroll
    for (int i = 0; i < EPB; ++i) {
        int e = base + i * ABLK + t;
        if (e < E) atomicAdd(&hist[dst[e] >> BUCKET_BITS], 1);
    }
    __syncthreads();
    if (t < NB) blkHist[blockIdx.x * NB + t] = hist[t];
}

// ---- Phase A2: column scans -> per-(block,bucket) local prefix (in place)
//      + bucket starts in off[] -------------------------------------------
__global__ void k_bases(int* __restrict__ blkHist, int* __restrict__ off,
                        int E, int NB, int nblk) {
    __shared__ int s[512];
    int t = threadIdx.x;
    int run = 0;
    if (t < NB) {
        for (int blk = 0; blk < nblk; ++blk) {
            int idx = blk * NB + t;
            int v = blkHist[idx];
            blkHist[idx] = run;      // prefix of earlier blocks within bucket t
            run += v;
        }
    }
    s[t] = (t < NB) ? run : 0;
    __syncthreads();
    #pragma unroll
    for (int d = 1; d < 512; d <<= 1) {
        int add = (t >= d) ? s[t - d] : 0;
        __syncthreads();
        s[t] += add;
        __syncthreads();
    }
    if (t < NB) off[t] = s[t] - run;   // exclusive bucket start
    if (t == 0) off[NB] = E;
}

// ---- Phase A3: stage chunk in LDS bucket-sorted, flush coalesced --------
__global__ void __launch_bounds__(ABLK) k_stage(const int* __restrict__ src,
                                                const int* __restrict__ dst,
                                                const int* __restrict__ blkHist,
                                                const int* __restrict__ off,
                                                int* __restrict__ csr, int E, int NB) {
    __shared__ int staged[CHUNK];            // 32 KB
    __shared__ unsigned short sbk[CHUNK];    // 16 KB
    __shared__ int hist[512];
    __shared__ int lbase[512];
    __shared__ int lcur[512];
    __shared__ int gbase[512];

    int t = threadIdx.x;
    hist[t] = 0;
    __syncthreads();

    int base = blockIdx.x * CHUNK;
    int bk[EPB], pk[EPB];
    #pragma unroll
    for (int i = 0; i < EPB; ++i) {
        int e = base + i * ABLK + t;
        int bb = -1, p = 0;
        if (e < E) {
            int d = dst[e];
            bb = d >> BUCKET_BITS;
            p = (src[e] << BUCKET_BITS) | (d & (BUCKET_SZ - 1));
            atomicAdd(&hist[bb], 1);
        }
        bk[i] = bb; pk[i] = p;
    }
    __syncthreads();

    // exclusive scan of hist -> lbase
    int v = hist[t];
    lbase[t] = v;   // reuse as scan buffer
    __syncthreads();
    #pragma unroll
    for (int d = 1; d < 512; d <<= 1) {
        int add = (t >= d) ? lbase[t - d] : 0;
        __syncthreads();
        lbase[t] += add;
        __syncthreads();
    }
    int excl = lbase[t] - v;
    __syncthreads();
    lbase[t] = excl;
    lcur[t] = excl;
    if (t < NB) gbase[t] = off[t] + blkHist[blockIdx.x * NB + t];
    __syncthreads();

    #pragma unroll
    for (int i = 0; i < EPB; ++i) {
        if (bk[i] >= 0) {
            int slot = atomicAdd(&lcur[bk[i]], 1);
            staged[slot] = pk[i];
            sbk[slot] = (unsigned short)bk[i];
        }
    }
    __syncthreads();

    int total = (base + CHUNK <= E) ? CHUNK : (E - base);
    for (int s2 = t; s2 < total; s2 += ABLK) {
        int bb = sbk[s2];
        csr[gbase[bb] + (s2 - lbase[bb])] = staged[s2];
    }
}

// ---- Phase B: per-bucket LDS accumulate + fused epilogue ----------------
__global__ void __launch_bounds__(512) k_aggregate(const float* __restrict__ g,
                                                   const int* __restrict__ off,
                                                   const int* __restrict__ csr,
                                                   const float* __restrict__ dis,
                                                   const float* __restrict__ bias,
                                                   float* __restrict__ out, int N, int NB) {
    __shared__ float acc[BUCKET_SZ * OUT_F];   // 32 KB
    int t = threadIdx.x;
    for (int i = t; i < BUCKET_SZ * OUT_F; i += 512) acc[i] = 0.f;
    __syncthreads();

    int b = blockIdx.x;
    int s0 = off[b], s1 = off[b + 1];
    int grp = t >> 5;          // 16 edge groups
    int f = t & 31;
    int j = s0 + grp;
    for (; j + 48 < s1; j += 64) {
        int p0 = csr[j];
        int p1 = csr[j + 16];
        int p2 = csr[j + 32];
        int p3 = csr[j + 48];
        float v0 = g[(p0 >> BUCKET_BITS) * OUT_F + f];
        float v1 = g[(p1 >> BUCKET_BITS) * OUT_F + f];
        float v2 = g[(p2 >> BUCKET_BITS) * OUT_F + f];
        float v3 = g[(p3 >> BUCKET_BITS) * OUT_F + f];
        atomicAdd(&acc[(p0 & (BUCKET_SZ - 1)) * OUT_F + f], v0);
        atomicAdd(&acc[(p1 & (BUCKET_SZ - 1)) * OUT_F + f], v1);
        atomicAdd(&acc[(p2 & (BUCKET_SZ - 1)) * OUT_F + f], v2);
        atomicAdd(&acc[(p3 & (BUCKET_SZ - 1)) * OUT_F + f], v3);
    }
    for (; j < s1; j += 16) {
        int p = csr[j];
        atomicAdd(&acc[(p & (BUCKET_SZ - 1)) * OUT_F + f], g[(p >> BUCKET_BITS) * OUT_F + f]);
    }
    __syncthreads();

    int n0 = b << BUCKET_BITS;
    for (int i = t; i < BUCKET_SZ * OUT_F; i += 512) {
        int node = n0 + (i >> 5);
        if (node < N) {
            int ff = i & 31;
            out[node * OUT_F + ff] = dis[node] * (acc[i] + g[node * OUT_F + ff]) + bias[ff];
        }
    }
}

extern "C" void kernel_launch(void* const* d_in, const int* in_sizes, int n_in,
                              void* d_out, int out_size, void* d_ws, size_t ws_size,
                              hipStream_t stream) {
    const float* x  = (const float*)d_in[0];
    const int*   ei = (const int*)d_in[1];
    const float* W  = (const float*)d_in[2];
    const float* b  = (const float*)d_in[3];
    float* out = (float*)d_out;

    int N = in_sizes[0] / IN_F;   // 100000
    int E = in_sizes[1] / 2;      // 1600000
    const int* src = ei;
    const int* dst = ei + E;

    int NB = (N + BUCKET_SZ - 1) >> BUCKET_BITS;      // 391
    int nblkA = (E + CHUNK - 1) / CHUNK;              // 196

    // workspace layout (all 128B-aligned given N,E multiples)
    char* p = (char*)d_ws;
    int*   cnt     = (int*)p;    p += (size_t)N * 4;
    float* dis     = (float*)p;  p += (size_t)N * 4;
    float* g       = (float*)p;  p += (size_t)N * OUT_F * 4;
    int*   csr     = (int*)p;    p += (size_t)E * 4;
    int*   blkHist = (int*)p;    p += (size_t)nblkA * NB * 4;
    int*   off     = (int*)p;    p += (size_t)(NB + 1) * 4;

    hipMemsetAsync(cnt, 0, (size_t)N * 4, stream);
    k_hist<<<(E + 255) / 256, 256, 0, stream>>>(dst, cnt, E);
    k_dis <<<(N + 255) / 256, 256, 0, stream>>>(cnt, dis, N);
    k_gemm<<<(N + 7) / 8, 256, 0, stream>>>(x, W, dis, g, N);

    k_bhist<<<nblkA, ABLK, 0, stream>>>(dst, blkHist, E, NB);
    k_bases<<<1, 512, 0, stream>>>(blkHist, off, E, NB, nblkA);
    k_stage<<<nblkA, ABLK, 0, stream>>>(src, dst, blkHist, off, csr, E, NB);
    k_aggregate<<<NB, 512, 0, stream>>>(g, off, csr, dis, b, out, N, NB);
}

// Round 5
// 361.359 us; speedup vs baseline: 1.8972x; 1.8972x over previous
//
#include <hip/hip_runtime.h>

#define IN_F 128
#define OUT_F 32

typedef unsigned int uint32;

// bf16 (in low 16 bits) -> f32
__device__ __forceinline__ float bf2f(uint32 u) {
    union { uint32 ui; float f; } c; c.ui = u << 16; return c.f;
}
// f32 -> bf16 bits, RNE
__device__ __forceinline__ uint32 f2bf(float x) {
    union { float f; uint32 ui; } c; c.f = x;
    uint32 u = c.ui;
    u += 0x7fffu + ((u >> 16) & 1u);
    return u >> 16;
}

// ---- degree histogram ---------------------------------------------------
__global__ void k_hist(const int* __restrict__ dst, int* __restrict__ cnt, int E) {
    int e = blockIdx.x * blockDim.x + threadIdx.x;
    if (e < E) atomicAdd(&cnt[dst[e]], 1);
}

// ---- fused gemm: h = x@W^T ; d = rsqrt(deg) ;
//      gbf = bf16(h*d) ; out = d*d*h + b  (self-loop init) ---------------
// block = 256 threads = 8 nodes x 32 features
__global__ void k_gemm(const float* __restrict__ x, const float* __restrict__ W,
                       const int* __restrict__ cnt, const float* __restrict__ b,
                       unsigned short* __restrict__ gbf, float* __restrict__ out, int n) {
    __shared__ float  Wl[IN_F * OUT_F];   // transposed: Wl[k*32 + f]
    __shared__ float4 xl4[8 * 32];

    int tid = threadIdx.x;
    for (int i = tid; i < IN_F * OUT_F; i += 256) {
        int f = i >> 7;
        int k = i & 127;
        Wl[k * 32 + f] = W[i];
    }
    int nodeBase = blockIdx.x * 8;
    int row = tid >> 5, c4 = tid & 31;
    int nrow = nodeBase + row;
    if (nrow < n) xl4[row * 32 + c4] = ((const float4*)x)[nrow * 32 + c4];
    __syncthreads();

    int f = tid & 31, nl = tid >> 5;
    int node = nodeBase + nl;
    if (node < n) {
        float acc = 0.f;
        #pragma unroll
        for (int k4 = 0; k4 < 32; ++k4) {
            float4 xv = xl4[nl * 32 + k4];
            int kb = k4 * 4;
            acc = fmaf(xv.x, Wl[(kb + 0) * 32 + f], acc);
            acc = fmaf(xv.y, Wl[(kb + 1) * 32 + f], acc);
            acc = fmaf(xv.z, Wl[(kb + 2) * 32 + f], acc);
            acc = fmaf(xv.w, Wl[(kb + 3) * 32 + f], acc);
        }
        float d = rsqrtf((float)(cnt[node] + 1));
        float g = acc * d;
        gbf[node * OUT_F + f] = (unsigned short)f2bf(g);  // bf16 bits
        out[node * OUT_F + f] = d * g + b[f];             // d^2*h + b
    }
}

// ---- scatter: accbf2[d*16+l] += bf16x2( g2[s*16+l] * dis[d] ) -----------
// 16 lanes per edge, 2 independent edges per thread (ILP)
__global__ void k_scatter(const uint32* __restrict__ g2, const int* __restrict__ src,
                          const int* __restrict__ dst, const int* __restrict__ cnt,
                          uint32* __restrict__ acc2, int Ehalf) {
    long long t = (long long)blockIdx.x * blockDim.x + threadIdx.x;
    int e0 = (int)(t >> 4);
    if (e0 >= Ehalf) return;
    int l  = (int)(t & 15);
    int e1 = e0 + Ehalf;

    int s0 = src[e0], d0 = dst[e0];
    int s1 = src[e1], d1 = dst[e1];
    uint32 v0 = g2[s0 * 16 + l];
    uint32 v1 = g2[s1 * 16 + l];
    int c0 = cnt[d0], c1 = cnt[d1];
    float w0 = rsqrtf((float)(c0 + 1));
    float w1 = rsqrtf((float)(c1 + 1));

    uint32 p0 = f2bf(bf2f(v0 & 0xffffu) * w0) | (f2bf(bf2f(v0 >> 16) * w0) << 16);
    uint32 p1 = f2bf(bf2f(v1 & 0xffffu) * w1) | (f2bf(bf2f(v1 >> 16) * w1) << 16);

    uint32* a0 = acc2 + (d0 * 16 + l);
    uint32* a1 = acc2 + (d1 * 16 + l);
    asm volatile("global_atomic_pk_add_bf16 %0, %1, off" :: "v"(a0), "v"(p0) : "memory");
    asm volatile("global_atomic_pk_add_bf16 %0, %1, off" :: "v"(a1), "v"(p1) : "memory");
}

// ---- final: out += f32(accbf) -------------------------------------------
__global__ void k_final(const uint32* __restrict__ acc2, float2* __restrict__ out2, int n16) {
    int i = blockIdx.x * blockDim.x + threadIdx.x;
    if (i < n16) {
        uint32 a = acc2[i];
        float2 o = out2[i];
        o.x += bf2f(a & 0xffffu);
        o.y += bf2f(a >> 16);
        out2[i] = o;
    }
}

extern "C" void kernel_launch(void* const* d_in, const int* in_sizes, int n_in,
                              void* d_out, int out_size, void* d_ws, size_t ws_size,
                              hipStream_t stream) {
    const float* x  = (const float*)d_in[0];
    const int*   ei = (const int*)d_in[1];
    const float* W  = (const float*)d_in[2];
    const float* b  = (const float*)d_in[3];
    float* out = (float*)d_out;

    int N = in_sizes[0] / IN_F;   // 100000
    int E = in_sizes[1] / 2;      // 1600000
    const int* src = ei;
    const int* dst = ei + E;

    // workspace: [cnt: N ints][accbf: N*32 bf16][gbf: N*32 bf16]
    char* p = (char*)d_ws;
    int*            cnt  = (int*)p;            p += (size_t)N * 4;
    uint32*         acc2 = (uint32*)p;         p += (size_t)N * OUT_F * 2;
    unsigned short* gbf  = (unsigned short*)p; p += (size_t)N * OUT_F * 2;

    // zero cnt + accbf in one shot (adjacent)
    (void)hipMemsetAsync(cnt, 0, (size_t)N * 4 + (size_t)N * OUT_F * 2, stream);

    k_hist<<<(E + 255) / 256, 256, 0, stream>>>(dst, cnt, E);
    k_gemm<<<(N + 7) / 8, 256, 0, stream>>>(x, W, cnt, b, gbf, out, N);

    int Ehalf = E / 2;
    long long tasks = (long long)Ehalf * 16;
    k_scatter<<<(int)((tasks + 255) / 256), 256, 0, stream>>>(
        (const uint32*)gbf, src, dst, cnt, acc2, Ehalf);

    int n16 = N * 16;
    k_final<<<(n16 + 255) / 256, 256, 0, stream>>>(acc2, (float2*)out, n16);
}